// Round 4
// baseline (88.826 us; speedup 1.0000x reference)
//
#include <hip/hip_runtime.h>
#include <math.h>

// Problem constants (from reference): N=256, D=128, C=1000, Q=262144
constexpr int  Nn = 256;
constexpr int  Dd = 128;
constexpr int  Cc = 1000;
constexpr int  Qq = 262144;
constexpr float PROTO_M = 0.99f;

// clang-native vector types (usable with __builtin_nontemporal_*)
typedef float vf4 __attribute__((ext_vector_type(4)));
typedef int   vi4 __attribute__((ext_vector_type(4)));

// ---- float4-unit segment sizes ----
constexpr long SEG_OUTX  = (long)Nn * Cc / 4;        // 64000   output_x copy
constexpr long SEG_QX    = (long)Nn * Dd / 4;        // 8192    q_x -> features
constexpr long SEG_QUEUE = (long)Qq * Dd / 4;        // 8388608 queue -> features + new_queue
constexpr long SEG_TGT   = (long)(2 * Nn + Qq) / 4;  // 65664   targets
constexpr long SEG_QY    = (long)Qq / 4;             // 65536   new_queue_Y / new_isID

// ---- output offsets in float units (tuple members flattened in order) ----
constexpr long OFF_OUTX = 0;
constexpr long OFF_FEAT = (long)Nn * Cc;                       // 256000
constexpr long OFF_TGT  = OFF_FEAT + (long)(2 * Nn + Qq) * Dd; // 33875968
constexpr long OFF_PROT = OFF_TGT + (2 * Nn + Qq);             // 34138624
constexpr long OFF_NQ   = OFF_PROT + (long)Cc * Dd;            // 34266624
constexpr long OFF_NQY  = OFF_NQ + (long)Qq * Dd;              // 67821056
constexpr long OFF_ISID = OFF_NQY + Qq;                        // 68083200
constexpr long OFF_PTR  = OFF_ISID + Qq;                       // 68345344

// ---- block-role partition ----
// Queue blocks: contiguous chunks of CH float4 units; CH is a multiple of 512
// (= 256 threads x 2 units per double-iteration). 8388608 = 3276*2560 + 2048,
// and 2048 is also a multiple of 512 -> NO remainder guards anywhere.
constexpr long CH       = 2560;
constexpr int  QBLOCKS  = (int)((SEG_QUEUE + CH - 1) / CH);    // 3277
constexpr int  OBLOCKS  = 512;                                  // small segments
constexpr int  PBLOCKS  = Cc / 2;                               // 500 proto blocks
constexpr long OTHER_TOTAL = SEG_OUTX + 2 * SEG_QX + SEG_TGT + 2 * SEG_QY + 1; // 277121

__global__ __launch_bounds__(256) void mega_kernel(
    const vf4* __restrict__ q_x4, const vf4* __restrict__ k_x4,
    const vf4* __restrict__ output_x4, const vf4* __restrict__ queue4,
    const float* __restrict__ protos, const vf4* __restrict__ isID4,
    const int* __restrict__ Y, const int* __restrict__ queue_Y,
    const int* __restrict__ ptr_p, float* __restrict__ out)
{
    vf4* out4 = (vf4*)out;
    const int bid = blockIdx.x;
    const int t   = threadIdx.x;

    const int ptr_raw = *ptr_p;
    const int ptr = min(max(ptr_raw, 0), Qq - Nn);   // dynamic_update_slice clamp

    // ================= queue blocks: the 97.6%-of-traffic hot path ============
    if (bid < QBLOCKS) {
        vf4* __restrict__ feat4 = out4 + OFF_FEAT / 4 + 2 * SEG_QX;
        vf4* __restrict__ nq4   = out4 + OFF_NQ / 4;
        const long s = (long)bid * CH;
        const long e = min(s + CH, SEG_QUEUE);
        for (long i = s + t; i < e; i += 512) {
            const long j = i + 256;                  // always < e (chunk % 512 == 0)
            vf4 a = __builtin_nontemporal_load(queue4 + i);
            vf4 b = __builtin_nontemporal_load(queue4 + j);
            __builtin_nontemporal_store(a, feat4 + i);
            __builtin_nontemporal_store(b, feat4 + j);
            const int rowa = (int)(i >> 5);          // D/4 = 32 float4 per row
            const int rowb = (int)(j >> 5);
            vf4 na = a, nb = b;
            if (rowa >= ptr && rowa < ptr + Nn)
                na = k_x4[((long)(rowa - ptr) << 5) + (i & 31)];
            if (rowb >= ptr && rowb < ptr + Nn)
                nb = k_x4[((long)(rowb - ptr) << 5) + (j & 31)];
            __builtin_nontemporal_store(na, nq4 + i);
            __builtin_nontemporal_store(nb, nq4 + j);
        }
        return;
    }

    // ================= small-segment blocks (3% of traffic) ===================
    if (bid < QBLOCKS + OBLOCKS) {
        const vi4* Y4  = (const vi4*)Y;
        const vi4* qY4 = (const vi4*)queue_Y;
        const long stride = (long)OBLOCKS * 256;
        for (long v = (long)(bid - QBLOCKS) * 256 + t; v < OTHER_TOTAL; v += stride) {
            long r = v;
            if (r < SEG_OUTX) {                      // output_x passthrough
                vf4 x = __builtin_nontemporal_load(output_x4 + r);
                __builtin_nontemporal_store(x, out4 + OFF_OUTX / 4 + r);
                continue;
            }
            r -= SEG_OUTX;
            if (r < SEG_QX) {                        // features[0:N] = q_x
                vf4 x = q_x4[r];
                __builtin_nontemporal_store(x, out4 + OFF_FEAT / 4 + r);
                continue;
            }
            r -= SEG_QX;
            if (r < SEG_QX) {                        // features[N:2N] = k_x
                vf4 x = k_x4[r];
                __builtin_nontemporal_store(x, out4 + OFF_FEAT / 4 + SEG_QX + r);
                continue;
            }
            r -= SEG_QX;
            if (r < SEG_TGT) {                       // targets = concat(Y,Y,queue_Y)
                vi4 x;
                if (r < Nn / 4)          x = Y4[r];
                else if (r < 2 * Nn / 4) x = Y4[r - Nn / 4];
                else                     x = qY4[r - 2 * Nn / 4];
                vf4 o = { (float)x.x, (float)x.y, (float)x.z, (float)x.w };
                __builtin_nontemporal_store(o, out4 + OFF_TGT / 4 + r);
                continue;
            }
            r -= SEG_TGT;
            if (r < SEG_QY) {                        // new_queue_Y with splice
                vi4 x = qY4[r];
                vf4 o = { (float)x.x, (float)x.y, (float)x.z, (float)x.w };
                long e0 = r << 2;
                if (e0 + 3 >= ptr && e0 < (long)ptr + Nn) {
                    #pragma unroll
                    for (int c2 = 0; c2 < 4; ++c2) {
                        long e = e0 + c2;
                        if (e >= ptr && e < (long)ptr + Nn) o[c2] = (float)Y[e - ptr];
                    }
                }
                __builtin_nontemporal_store(o, out4 + OFF_NQY / 4 + r);
                continue;
            }
            r -= SEG_QY;
            if (r < SEG_QY) {                        // new_isID with splice
                vf4 o = __builtin_nontemporal_load(isID4 + r);
                long e0 = r << 2;
                if (e0 + 3 >= ptr && e0 < (long)ptr + Nn) {
                    #pragma unroll
                    for (int c2 = 0; c2 < 4; ++c2) {
                        long e = e0 + c2;
                        if (e >= ptr && e < (long)ptr + Nn) o[c2] = 1.0f;
                    }
                }
                __builtin_nontemporal_store(o, out4 + OFF_ISID / 4 + r);
                continue;
            }
            out[OFF_PTR] = (float)((ptr_raw + Nn) % Qq);   // new_ptr
        }
        return;
    }

    // ================= prototype EMA + renormalize (latency-bound) ============
    {
        const float* q_x = (const float*)q_x4;
        const int grp = t >> 7;                      // 0 or 1: which class
        const int c   = (bid - QBLOCKS - OBLOCKS) * 2 + grp;
        const int d   = t & 127;
        float p = protos[(long)c * Dd + d];
        const float m = PROTO_M, om = 1.0f - PROTO_M;
        for (int i = 0; i < Nn; ++i) {
            int y = Y[i];                            // wave-uniform, L2-hot
            if (y == c) p = m * p + om * q_x[(long)i * Dd + d];
        }
        float s = p * p;                             // 128-thread sum of squares
        #pragma unroll
        for (int off = 32; off >= 1; off >>= 1) s += __shfl_xor(s, off);
        __shared__ float ws[4];
        if ((t & 63) == 0) ws[t >> 6] = s;
        __syncthreads();
        float norm = fmaxf(sqrtf(ws[2 * grp] + ws[2 * grp + 1]), 1e-12f);
        out[OFF_PROT + (long)c * Dd + d] = p / norm;
    }
}

extern "C" void kernel_launch(void* const* d_in, const int* in_sizes, int n_in,
                              void* d_out, int out_size, void* d_ws, size_t ws_size,
                              hipStream_t stream)
{
    const float* q_x      = (const float*)d_in[0];
    const float* k_x      = (const float*)d_in[1];
    const float* output_x = (const float*)d_in[2];
    const float* queue    = (const float*)d_in[3];
    const float* protos   = (const float*)d_in[4];
    const float* isID     = (const float*)d_in[5];
    const int*   Y        = (const int*)d_in[6];
    const int*   queue_Y  = (const int*)d_in[7];
    const int*   ptr_p    = (const int*)d_in[8];
    float* out = (float*)d_out;

    hipLaunchKernelGGL(mega_kernel, dim3(QBLOCKS + OBLOCKS + PBLOCKS), dim3(256), 0, stream,
                       (const vf4*)q_x, (const vf4*)k_x,
                       (const vf4*)output_x, (const vf4*)queue,
                       protos, (const vf4*)isID, Y, queue_Y, ptr_p, out);
}

// Round 5
// 83.454 us; speedup vs baseline: 1.0644x; 1.0644x over previous
//
#include <hip/hip_runtime.h>
#include <math.h>

// Problem constants (from reference): N=256, D=128, C=1000, Q=262144
constexpr int  Nn = 256;
constexpr int  Dd = 128;
constexpr int  Cc = 1000;
constexpr int  Qq = 262144;
constexpr float PROTO_M = 0.99f;

// clang-native vector types (usable with __builtin_nontemporal_*)
typedef float vf4 __attribute__((ext_vector_type(4)));
typedef int   vi4 __attribute__((ext_vector_type(4)));

// ---- float4-unit segment sizes ----
constexpr long SEG_OUTX  = (long)Nn * Cc / 4;        // 64000   output_x copy
constexpr long SEG_QX    = (long)Nn * Dd / 4;        // 8192    q_x -> features
constexpr long SEG_QUEUE = (long)Qq * Dd / 4;        // 8388608 queue -> features + new_queue
constexpr long SEG_TGT   = (long)(2 * Nn + Qq) / 4;  // 65664   targets
constexpr long SEG_QY    = (long)Qq / 4;             // 65536   new_queue_Y / new_isID

// ---- output offsets in float units (tuple members flattened in order) ----
constexpr long OFF_OUTX = 0;
constexpr long OFF_FEAT = (long)Nn * Cc;                       // 256000
constexpr long OFF_TGT  = OFF_FEAT + (long)(2 * Nn + Qq) * Dd; // 33875968
constexpr long OFF_PROT = OFF_TGT + (2 * Nn + Qq);             // 34138624
constexpr long OFF_NQ   = OFF_PROT + (long)Cc * Dd;            // 34266624
constexpr long OFF_NQY  = OFF_NQ + (long)Qq * Dd;              // 67821056
constexpr long OFF_ISID = OFF_NQY + Qq;                        // 68083200
constexpr long OFF_PTR  = OFF_ISID + Qq;                       // 68345344

// ---- block-role partition: latency-bound work FIRST so it hides under the
// BW-bound queue streaming (R4 lesson: roles at the grid tail run naked). ----
constexpr int  PBLOCKS  = Cc / 2;                               // 500 proto blocks
constexpr int  OBLOCKS  = 512;                                  // small segments
// Queue blocks: contiguous chunks of CH float4 units; CH multiple of 512
// (= 256 threads x 2 units per double-iteration). 8388608 = 3276*2560 + 2048,
// 2048 also a multiple of 512 -> no remainder guards anywhere.
constexpr long CH       = 2560;
constexpr int  QBLOCKS  = (int)((SEG_QUEUE + CH - 1) / CH);     // 3277
constexpr long OTHER_TOTAL = SEG_OUTX + 2 * SEG_QX + SEG_TGT + 2 * SEG_QY + 1; // 277121

__global__ __launch_bounds__(256) void mega_kernel(
    const vf4* __restrict__ q_x4, const vf4* __restrict__ k_x4,
    const vf4* __restrict__ output_x4, const vf4* __restrict__ queue4,
    const float* __restrict__ protos, const vf4* __restrict__ isID4,
    const int* __restrict__ Y, const int* __restrict__ queue_Y,
    const int* __restrict__ ptr_p, float* __restrict__ out)
{
    vf4* out4 = (vf4*)out;
    const int bid = blockIdx.x;
    const int t   = threadIdx.x;

    const int ptr_raw = *ptr_p;
    const int ptr = min(max(ptr_raw, 0), Qq - Nn);   // dynamic_update_slice clamp

    // ================= prototype EMA + renormalize (latency-bound, FIRST) =====
    if (bid < PBLOCKS) {
        const float* q_x = (const float*)q_x4;
        const int grp = t >> 7;                      // 0 or 1: which class
        const int c   = bid * 2 + grp;
        const int d   = t & 127;
        float p = protos[(long)c * Dd + d];
        const float m = PROTO_M, om = 1.0f - PROTO_M;
        for (int i = 0; i < Nn; ++i) {
            int y = Y[i];                            // wave-uniform, L2-hot
            if (y == c) p = m * p + om * q_x[(long)i * Dd + d];
        }
        float s = p * p;                             // 128-thread sum of squares
        #pragma unroll
        for (int off = 32; off >= 1; off >>= 1) s += __shfl_xor(s, off);
        __shared__ float ws[4];
        if ((t & 63) == 0) ws[t >> 6] = s;
        __syncthreads();
        float norm = fmaxf(sqrtf(ws[2 * grp] + ws[2 * grp + 1]), 1e-12f);
        out[OFF_PROT + (long)c * Dd + d] = p / norm;
        return;
    }

    // ================= small-segment blocks (3% of traffic) ===================
    if (bid < PBLOCKS + OBLOCKS) {
        const vi4* Y4  = (const vi4*)Y;
        const vi4* qY4 = (const vi4*)queue_Y;
        const long stride = (long)OBLOCKS * 256;
        for (long v = (long)(bid - PBLOCKS) * 256 + t; v < OTHER_TOTAL; v += stride) {
            long r = v;
            if (r < SEG_OUTX) {                      // output_x passthrough
                vf4 x = __builtin_nontemporal_load(output_x4 + r);
                __builtin_nontemporal_store(x, out4 + OFF_OUTX / 4 + r);
                continue;
            }
            r -= SEG_OUTX;
            if (r < SEG_QX) {                        // features[0:N] = q_x
                vf4 x = q_x4[r];
                __builtin_nontemporal_store(x, out4 + OFF_FEAT / 4 + r);
                continue;
            }
            r -= SEG_QX;
            if (r < SEG_QX) {                        // features[N:2N] = k_x
                vf4 x = k_x4[r];
                __builtin_nontemporal_store(x, out4 + OFF_FEAT / 4 + SEG_QX + r);
                continue;
            }
            r -= SEG_QX;
            if (r < SEG_TGT) {                       // targets = concat(Y,Y,queue_Y)
                vi4 x;
                if (r < Nn / 4)          x = Y4[r];
                else if (r < 2 * Nn / 4) x = Y4[r - Nn / 4];
                else                     x = qY4[r - 2 * Nn / 4];
                vf4 o = { (float)x.x, (float)x.y, (float)x.z, (float)x.w };
                __builtin_nontemporal_store(o, out4 + OFF_TGT / 4 + r);
                continue;
            }
            r -= SEG_TGT;
            if (r < SEG_QY) {                        // new_queue_Y with splice
                vi4 x = qY4[r];
                vf4 o = { (float)x.x, (float)x.y, (float)x.z, (float)x.w };
                long e0 = r << 2;
                if (e0 + 3 >= ptr && e0 < (long)ptr + Nn) {
                    #pragma unroll
                    for (int c2 = 0; c2 < 4; ++c2) {
                        long e = e0 + c2;
                        if (e >= ptr && e < (long)ptr + Nn) o[c2] = (float)Y[e - ptr];
                    }
                }
                __builtin_nontemporal_store(o, out4 + OFF_NQY / 4 + r);
                continue;
            }
            r -= SEG_QY;
            if (r < SEG_QY) {                        // new_isID with splice
                vf4 o = __builtin_nontemporal_load(isID4 + r);
                long e0 = r << 2;
                if (e0 + 3 >= ptr && e0 < (long)ptr + Nn) {
                    #pragma unroll
                    for (int c2 = 0; c2 < 4; ++c2) {
                        long e = e0 + c2;
                        if (e >= ptr && e < (long)ptr + Nn) o[c2] = 1.0f;
                    }
                }
                __builtin_nontemporal_store(o, out4 + OFF_ISID / 4 + r);
                continue;
            }
            out[OFF_PTR] = (float)((ptr_raw + Nn) % Qq);   // new_ptr
        }
        return;
    }

    // ================= queue blocks: the 97.6%-of-traffic hot path ============
    {
        vf4* __restrict__ feat4 = out4 + OFF_FEAT / 4 + 2 * SEG_QX;
        vf4* __restrict__ nq4   = out4 + OFF_NQ / 4;
        const long s = (long)(bid - PBLOCKS - OBLOCKS) * CH;
        const long e = min(s + CH, SEG_QUEUE);
        for (long i = s + t; i < e; i += 512) {
            const long j = i + 256;                  // always < e (chunk % 512 == 0)
            vf4 a = __builtin_nontemporal_load(queue4 + i);
            vf4 b = __builtin_nontemporal_load(queue4 + j);
            __builtin_nontemporal_store(a, feat4 + i);
            __builtin_nontemporal_store(b, feat4 + j);
            const int rowa = (int)(i >> 5);          // D/4 = 32 float4 per row
            const int rowb = (int)(j >> 5);
            vf4 na = a, nb = b;
            if (rowa >= ptr && rowa < ptr + Nn)
                na = k_x4[((long)(rowa - ptr) << 5) + (i & 31)];
            if (rowb >= ptr && rowb < ptr + Nn)
                nb = k_x4[((long)(rowb - ptr) << 5) + (j & 31)];
            __builtin_nontemporal_store(na, nq4 + i);
            __builtin_nontemporal_store(nb, nq4 + j);
        }
    }
}

extern "C" void kernel_launch(void* const* d_in, const int* in_sizes, int n_in,
                              void* d_out, int out_size, void* d_ws, size_t ws_size,
                              hipStream_t stream)
{
    const float* q_x      = (const float*)d_in[0];
    const float* k_x      = (const float*)d_in[1];
    const float* output_x = (const float*)d_in[2];
    const float* queue    = (const float*)d_in[3];
    const float* protos   = (const float*)d_in[4];
    const float* isID     = (const float*)d_in[5];
    const int*   Y        = (const int*)d_in[6];
    const int*   queue_Y  = (const int*)d_in[7];
    const int*   ptr_p    = (const int*)d_in[8];
    float* out = (float*)d_out;

    hipLaunchKernelGGL(mega_kernel, dim3(PBLOCKS + OBLOCKS + QBLOCKS), dim3(256), 0, stream,
                       (const vf4*)q_x, (const vf4*)k_x,
                       (const vf4*)output_x, (const vf4*)queue,
                       protos, (const vf4*)isID, Y, queue_Y, ptr_p, out);
}